// Round 1
// 251.886 us; speedup vs baseline: 1.0424x; 1.0424x over previous
//
#include <hip/hip_runtime.h>
#include <hip/hip_fp16.h>
#include <math.h>

#define N4C 32768
#define N3C 65536
#define N2C 131072
#define N1C 262144

typedef _Float16 f16x8 __attribute__((ext_vector_type(8)));
typedef float f32x4 __attribute__((ext_vector_type(4)));
typedef float f32x16 __attribute__((ext_vector_type(16)));

__device__ __forceinline__ f32x4 mfma16(f16x8 a, f16x8 b, f32x4 c) {
  return __builtin_amdgcn_mfma_f32_16x16x32_f16(a, b, c, 0, 0, 0);
}
__device__ __forceinline__ f32x16 mfma32(f16x8 a, f16x8 b, f32x16 c) {
  return __builtin_amdgcn_mfma_f32_32x32x16_f16(a, b, c, 0, 0, 0);
}

// fast celu (f32): max(x,0) + expm1(min(x,0)), branch-free
__device__ __forceinline__ float celuf(float x) {
  return fmaxf(x, 0.f) + (__expf(fminf(x, 0.f)) - 1.f);
}

__device__ __forceinline__ float logsigf(float x) {
  float e = __expf(-fabsf(x));
  return fminf(x, 0.f) - __logf(1.f + e);
}

// f16 exp via hexp (ocml v_exp_f16 path)
__device__ __forceinline__ _Float16 exp16(_Float16 x) {
  __half h; __builtin_memcpy(&h, &x, 2);
  h = hexp(h);
  _Float16 r; __builtin_memcpy(&r, &h, 2);
  return r;
}

// packed celu on 8 halfs: max(x,0) + (exp(min(x,0)) - 1)
__device__ __forceinline__ f16x8 celu8(f16x8 x) {
  f16x8 z = {};
  f16x8 mx = __builtin_elementwise_max(x, z);
  f16x8 mn = __builtin_elementwise_min(x, z);
#pragma unroll
  for (int i = 0; i < 8; ++i) mn[i] = exp16(mn[i]);
  return mx + (mn - (_Float16)1.0f);
}

// ---------------------------------------------------------------------------
// y4 = z @ W1a[:64] + b1a + pos4 @ W1a[64:67]  ([N4][64] f16)
// Position-folded: the rel-position source contribution is linear, so it is
// baked into the per-source-point table here (coalesced, ~free) instead of
// being re-gathered per edge in l3.
// ---------------------------------------------------------------------------
__global__ __launch_bounds__(256) void y4_kernel(
    const float* __restrict__ z, const float* __restrict__ pos4,
    const float* __restrict__ w1a, const float* __restrict__ b1a,
    _Float16* __restrict__ y4) {
  const int lane = threadIdx.x & 63, wid = threadIdx.x >> 6;
  const int col = lane & 15, quad = lane >> 4;
  const int base = (blockIdx.x * 4 + wid) * 16;

  f16x8 Ba[2][4];
#pragma unroll
  for (int c = 0; c < 2; ++c)
#pragma unroll
    for (int t = 0; t < 4; ++t)
#pragma unroll
      for (int j = 0; j < 8; ++j)
        Ba[c][t][j] = (_Float16)w1a[(c * 32 + quad * 8 + j) * 64 + t * 16 + col];

  // rel-weight rows 64..66 for this lane's 4 t-columns
  float wr[3][4];
#pragma unroll
  for (int c = 0; c < 3; ++c)
#pragma unroll
    for (int t = 0; t < 4; ++t)
      wr[c][t] = w1a[(64 + c) * 64 + t * 16 + col];

  // positions for this lane's 4 output rows
  float px[4], py[4], pz[4];
#pragma unroll
  for (int r = 0; r < 4; ++r) {
    const int row = base + quad * 4 + r;
    px[r] = pos4[row * 3 + 0];
    py[r] = pos4[row * 3 + 1];
    pz[r] = pos4[row * 3 + 2];
  }

  const float* zr = z + (size_t)(base + col) * 64;
  f16x8 A0, A1;
  {
    float4 f0 = *(const float4*)(zr + quad * 8);
    float4 f1 = *(const float4*)(zr + quad * 8 + 4);
    float4 f2 = *(const float4*)(zr + 32 + quad * 8);
    float4 f3 = *(const float4*)(zr + 32 + quad * 8 + 4);
    A0[0] = (_Float16)f0.x; A0[1] = (_Float16)f0.y; A0[2] = (_Float16)f0.z; A0[3] = (_Float16)f0.w;
    A0[4] = (_Float16)f1.x; A0[5] = (_Float16)f1.y; A0[6] = (_Float16)f1.z; A0[7] = (_Float16)f1.w;
    A1[0] = (_Float16)f2.x; A1[1] = (_Float16)f2.y; A1[2] = (_Float16)f2.z; A1[3] = (_Float16)f2.w;
    A1[4] = (_Float16)f3.x; A1[5] = (_Float16)f3.y; A1[6] = (_Float16)f3.z; A1[7] = (_Float16)f3.w;
  }
#pragma unroll
  for (int t = 0; t < 4; ++t) {
    f32x4 acc = {0.f, 0.f, 0.f, 0.f};
    acc = mfma16(A0, Ba[0][t], acc);
    acc = mfma16(A1, Ba[1][t], acc);
    const float bt = b1a[t * 16 + col];
#pragma unroll
    for (int r = 0; r < 4; ++r) {
      const float posterm =
          px[r] * wr[0][t] + py[r] * wr[1][t] + pz[r] * wr[2][t];
      y4[(size_t)(base + quad * 4 + r) * 64 + t * 16 + col] =
          (_Float16)(acc[r] + bt + posterm);
    }
  }
}

// ---------------------------------------------------------------------------
// y3 = x3 @ W2a[:32] + b2a + pos3 @ W2a[32:35]  ([N3][16] f16)
// ---------------------------------------------------------------------------
__global__ __launch_bounds__(256) void y3_kernel(
    const _Float16* __restrict__ x3f, const float* __restrict__ pos3,
    const float* __restrict__ w2a, const float* __restrict__ b2a,
    _Float16* __restrict__ y3) {
  const int lane = threadIdx.x & 63, wid = threadIdx.x >> 6;
  const int col = lane & 15, quad = lane >> 4;
  const int base = (blockIdx.x * 4 + wid) * 16;

  f16x8 B;
#pragma unroll
  for (int j = 0; j < 8; ++j) B[j] = (_Float16)w2a[(quad * 8 + j) * 16 + col];

  float wr[3];
#pragma unroll
  for (int c = 0; c < 3; ++c) wr[c] = w2a[(32 + c) * 16 + col];

  float px[4], py[4], pz[4];
#pragma unroll
  for (int r = 0; r < 4; ++r) {
    const int row = base + quad * 4 + r;
    px[r] = pos3[row * 3 + 0];
    py[r] = pos3[row * 3 + 1];
    pz[r] = pos3[row * 3 + 2];
  }

  f16x8 A = *(const f16x8*)(x3f + (size_t)(base + col) * 32 + quad * 8);
  f32x4 d = {0.f, 0.f, 0.f, 0.f};
  d = mfma16(A, B, d);
  const float bt = b2a[col];
#pragma unroll
  for (int r = 0; r < 4; ++r) {
    const float posterm = px[r] * wr[0] + py[r] * wr[1] + pz[r] * wr[2];
    y3[(size_t)(base + quad * 4 + r) * 16 + col] =
        (_Float16)(d[r] + bt + posterm);
  }
}

// ---------------------------------------------------------------------------
// y2 = x2 @ W3a[:16] + b3a + pos2 @ W3a[16:19]  ([N2][8] f16)
// ---------------------------------------------------------------------------
__global__ __launch_bounds__(256) void y2_kernel(
    const _Float16* __restrict__ x2f, const float* __restrict__ pos2,
    const float* __restrict__ w3a, const float* __restrict__ b3a,
    _Float16* __restrict__ y2) {
  const int lane = threadIdx.x & 63, wid = threadIdx.x >> 6;
  const int col = lane & 15, quad = lane >> 4;
  const int base = (blockIdx.x * 4 + wid) * 16;

  f16x8 B;
#pragma unroll
  for (int j = 0; j < 8; ++j) {
    int k = quad * 8 + j;
    B[j] = (k < 16 && col < 8) ? (_Float16)w3a[k * 8 + col] : (_Float16)0.f;
  }
  f16x8 A = *(const f16x8*)(x2f + (size_t)(base + col) * 16 + (quad & 1) * 8);
  f32x4 d = {0.f, 0.f, 0.f, 0.f};
  d = mfma16(A, B, d);
  if (col < 8) {
    float wr[3];
#pragma unroll
    for (int c = 0; c < 3; ++c) wr[c] = w3a[(16 + c) * 8 + col];
    const float bt = b3a[col];
#pragma unroll
    for (int r = 0; r < 4; ++r) {
      const int row = base + quad * 4 + r;
      const float posterm = pos2[row * 3 + 0] * wr[0] +
                            pos2[row * 3 + 1] * wr[1] +
                            pos2[row * 3 + 2] * wr[2];
      y2[(size_t)row * 8 + col] = (_Float16)(d[r] + bt + posterm);
    }
  }
}

// ---------------------------------------------------------------------------
// Level 3 gather: h = celu(Y4'[s] - v3(p)), 4 MFMA, max.
// Y4' already holds the source-position projection; only the (per-point,
// loop-invariant) destination projection v3 = pos3[p]·W1a[64:67] remains.
// ---------------------------------------------------------------------------
__global__ __launch_bounds__(256) void l3_kernel(
    const _Float16* __restrict__ y4, const float* __restrict__ pos3,
    const int* __restrict__ src3, const float* __restrict__ w1a,
    const float* __restrict__ w1b, const float* __restrict__ b1b,
    _Float16* __restrict__ x3f) {
  const int lane = threadIdx.x & 63, wid = threadIdx.x >> 6;
  const int col = lane & 15, quad = lane >> 4;

  f16x8 Bb[2][2];
#pragma unroll
  for (int c = 0; c < 2; ++c)
#pragma unroll
    for (int t = 0; t < 2; ++t)
#pragma unroll
      for (int j = 0; j < 8; ++j)
        Bb[c][t][j] = (_Float16)w1b[(c * 32 + quad * 8 + j) * 32 + t * 16 + col];
  f16x8 W0[3], W1[3];
#pragma unroll
  for (int c = 0; c < 3; ++c)
#pragma unroll
    for (int j = 0; j < 8; ++j) {
      W0[c][j] = (_Float16)w1a[(64 + c) * 64 + quad * 8 + j];
      W1[c][j] = (_Float16)w1a[(64 + c) * 64 + 32 + quad * 8 + j];
    }
  const float biasB0 = b1b[col], biasB1 = b1b[16 + col];

  const int gwave = blockIdx.x * 4 + wid;
  const int nw = gridDim.x * 4;

  for (int p = gwave; p < N3C; p += nw) {
    const int s = src3[p * 16 + col];
    const int up = __builtin_amdgcn_readfirstlane(p);
    const _Float16 q0 = (_Float16)pos3[up * 3 + 0];
    const _Float16 q1 = (_Float16)pos3[up * 3 + 1];
    const _Float16 q2 = (_Float16)pos3[up * 3 + 2];

    f16x8 A0 = *(const f16x8*)(y4 + (size_t)s * 64 + quad * 8);
    f16x8 A1 = *(const f16x8*)(y4 + (size_t)s * 64 + 32 + quad * 8);

    const f16x8 v0 = W0[0] * q0 + W0[1] * q1 + W0[2] * q2;
    const f16x8 v1 = W1[0] * q0 + W1[1] * q1 + W1[2] * q2;

    A0 = celu8(A0 - v0);
    A1 = celu8(A1 - v1);

    f32x4 e[2];
#pragma unroll
    for (int t = 0; t < 2; ++t) {
      f32x4 acc = {0.f, 0.f, 0.f, 0.f};
      acc = mfma16(A0, Bb[0][t], acc);
      acc = mfma16(A1, Bb[1][t], acc);
      e[t] = acc;
    }
    float m0 = fmaxf(fmaxf(e[0][0], e[0][1]), fmaxf(e[0][2], e[0][3]));
    float m1 = fmaxf(fmaxf(e[1][0], e[1][1]), fmaxf(e[1][2], e[1][3]));
    m0 = fmaxf(m0, __shfl_xor(m0, 16, 64));
    m0 = fmaxf(m0, __shfl_xor(m0, 32, 64));
    m1 = fmaxf(m1, __shfl_xor(m1, 16, 64));
    m1 = fmaxf(m1, __shfl_xor(m1, 32, 64));
    if (lane < 16) {
      _Float16* row = x3f + (size_t)p * 32;
      row[col]      = (_Float16)celuf(m0 + biasB0);
      row[16 + col] = (_Float16)celuf(m1 + biasB1);
    }
  }
}

// ---------------------------------------------------------------------------
// Level 2 gather: 2 points per wave via mfma_32x32x16, position-folded.
// ---------------------------------------------------------------------------
__global__ __launch_bounds__(256) void l2_kernel(
    const _Float16* __restrict__ y3, const float* __restrict__ pos2,
    const int* __restrict__ src2, const float* __restrict__ w2a,
    const float* __restrict__ w2b, const float* __restrict__ b2b,
    _Float16* __restrict__ x2f) {
  const int lane = threadIdx.x & 63, wid = threadIdx.x >> 6;
  const int n = lane & 31;
  const int e = lane & 15;
  const int h = (lane >> 4) & 1;
  const int kh = lane >> 5;

  f16x8 Bb;
#pragma unroll
  for (int j = 0; j < 8; ++j)
    Bb[j] = (n < 16) ? (_Float16)w2b[(kh * 8 + j) * 16 + n] : (_Float16)0.f;
  f16x8 W[3];
#pragma unroll
  for (int c = 0; c < 3; ++c)
#pragma unroll
    for (int j = 0; j < 8; ++j)
      W[c][j] = (_Float16)w2a[(32 + c) * 16 + kh * 8 + j];
  const float biasB = b2b[n & 15];

  const int gwave = blockIdx.x * 4 + wid;
  const int nw = gridDim.x * 4;

  for (int pr = gwave; pr < N2C / 2; pr += nw) {
    const int p = 2 * pr + h;
    const int s = src2[p * 16 + e];

    const _Float16 q0 = (_Float16)pos2[p * 3 + 0];
    const _Float16 q1 = (_Float16)pos2[p * 3 + 1];
    const _Float16 q2 = (_Float16)pos2[p * 3 + 2];

    f16x8 A = *(const f16x8*)(y3 + (size_t)s * 16 + kh * 8);
    const f16x8 v = W[0] * q0 + W[1] * q1 + W[2] * q2;
    A = celu8(A - v);

    f32x16 acc = {};
    acc = mfma32(A, Bb, acc);

    float mA = acc[0], mB = acc[8];
#pragma unroll
    for (int r = 1; r < 8; ++r) {
      mA = fmaxf(mA, acc[r]);
      mB = fmaxf(mB, acc[8 + r]);
    }
    mA = fmaxf(mA, __shfl_xor(mA, 32, 64));
    mB = fmaxf(mB, __shfl_xor(mB, 32, 64));

    if (n < 16) {
      const float m = kh ? mB : mA;
      x2f[(size_t)(2 * pr + kh) * 16 + n] = (_Float16)celuf(m + biasB);
    }
  }
}

// ---------------------------------------------------------------------------
// Level 1 gather: 4 points per wave via block-diagonal mfma_32x32x16,
// position-folded: per-edge work is one 16B gather + pk_sub + celu8 + mfma.
// ---------------------------------------------------------------------------
__global__ __launch_bounds__(256) void l1_kernel(
    const _Float16* __restrict__ y2, const float* __restrict__ pos1,
    const int* __restrict__ src1, const float* __restrict__ w3a,
    const float* __restrict__ w3b, const float* __restrict__ b3b,
    const float* __restrict__ wlin, const float* __restrict__ blin,
    float* __restrict__ out) {
  const int lane = threadIdx.x & 63, wid = threadIdx.x >> 6;
  const int m = lane & 31;        // A row = edge + 16*h
  const int e = lane & 15;        // edge
  const int h = (lane >> 4) & 1;  // m-half point selector
  const int kh = lane >> 5;       // k-half point selector
  const int g = 2 * kh + h;       // point within quad (0..3)

  // B block-diagonal: live iff n<16 and (n>>3)==k-half; out-ch = n&7
  f16x8 Bb;
  const int n = m;  // B col index for this lane
#pragma unroll
  for (int j = 0; j < 8; ++j)
    Bb[j] = (n < 16 && (n >> 3) == kh) ? (_Float16)w3b[j * 8 + (n & 7)]
                                       : (_Float16)0.f;
  // rel weights: k-within-point = j for both k-halves
  f16x8 W[3];
#pragma unroll
  for (int c = 0; c < 3; ++c)
#pragma unroll
    for (int j = 0; j < 8; ++j)
      W[c][j] = (_Float16)w3a[(16 + c) * 8 + j];
  const float biasB = (n < 16) ? b3b[n & 7] : 0.f;
  const float wl = (n < 16) ? wlin[n & 7] : 0.f;
  const float bl = blin[0];

  const int gwave = blockIdx.x * 4 + wid;
  const int nw = gridDim.x * 4;

  for (int q = gwave; q < N1C / 4; q += nw) {
    const int pb = q * 4;
    const int p = pb + g;
    const int s = src1[p * 16 + e];  // lane->offset g*16+e: coalesced window

    const _Float16 q0 = (_Float16)pos1[p * 3 + 0];
    const _Float16 q1 = (_Float16)pos1[p * 3 + 1];
    const _Float16 q2 = (_Float16)pos1[p * 3 + 2];

    f16x8 A = *(const f16x8*)(y2 + (size_t)s * 8);
    const f16x8 v = W[0] * q0 + W[1] * q1 + W[2] * q2;
    A = celu8(A - v);

    f32x16 acc = {};
    acc = mfma32(A, Bb, acc);

    // regs 0..7 = m rows 0..15 (h=0 points), regs 8..15 = m 16..31 (h=1)
    float mA = acc[0], mB = acc[8];
#pragma unroll
    for (int r = 1; r < 8; ++r) {
      mA = fmaxf(mA, acc[r]);
      mB = fmaxf(mB, acc[8 + r]);
    }
    mA = fmaxf(mA, __shfl_xor(mA, 32, 64));
    mB = fmaxf(mB, __shfl_xor(mB, 32, 64));
    // col n<8: k-half-0 points (g = 0 via mA, 1 via mB)
    // col 8..15: k-half-1 points (g = 2 via mA, 3 via mB)
    float tA = celuf(mA + biasB) * wl;   // wl==0 for n>=16
    float tB = celuf(mB + biasB) * wl;
    tA += __shfl_xor(tA, 1, 64);
    tA += __shfl_xor(tA, 2, 64);
    tA += __shfl_xor(tA, 4, 64);
    tB += __shfl_xor(tB, 1, 64);
    tB += __shfl_xor(tB, 2, 64);
    tB += __shfl_xor(tB, 4, 64);
    if (lane == 0) {   // points 0 (mA) and 1 (mB)
      float2 o; o.x = logsigf(tA + bl); o.y = logsigf(tB + bl);
      *(float2*)(out + pb) = o;
    } else if (lane == 8) {  // points 2 (mA) and 3 (mB)
      float2 o; o.x = logsigf(tA + bl); o.y = logsigf(tB + bl);
      *(float2*)(out + pb + 2) = o;
    }
  }
}

extern "C" void kernel_launch(void* const* d_in, const int* in_sizes, int n_in,
                              void* d_out, int out_size, void* d_ws, size_t ws_size,
                              hipStream_t stream) {
  const float* z_mask = (const float*)d_in[0];
  const float* pos4 = (const float*)d_in[1];
  const float* pos3 = (const float*)d_in[2];
  const float* pos2 = (const float*)d_in[3];
  const float* pos1 = (const float*)d_in[4];
  const float* w1a = (const float*)d_in[9];
  const float* b1a = (const float*)d_in[10];
  const float* w1b = (const float*)d_in[11];
  const float* b1b = (const float*)d_in[12];
  const float* w2a = (const float*)d_in[13];
  const float* b2a = (const float*)d_in[14];
  const float* w2b = (const float*)d_in[15];
  const float* b2b = (const float*)d_in[16];
  const float* w3a = (const float*)d_in[17];
  const float* b3a = (const float*)d_in[18];
  const float* w3b = (const float*)d_in[19];
  const float* b3b = (const float*)d_in[20];
  const float* wlin = (const float*)d_in[21];
  const float* blin = (const float*)d_in[22];
  const int* src3 = (const int*)d_in[23];
  const int* src2 = (const int*)d_in[25];
  const int* src1 = (const int*)d_in[27];

  // ws (16 MB): Y4 4 | x3f 4 | Y3 2 | x2f 4 | Y2 2
  char* w = (char*)d_ws;
  _Float16* y4  = (_Float16*)(w);                      // [N4][64]
  _Float16* x3f = (_Float16*)(w + (4u << 20));         // [N3][32]
  _Float16* y3  = (_Float16*)(w + (8u << 20));         // [N3][16]
  _Float16* x2f = (_Float16*)(w + (10u << 20));        // [N2][16]
  _Float16* y2  = (_Float16*)(w + (14u << 20));        // [N2][8]
  float* out = (float*)d_out;

  y4_kernel<<<512, 256, 0, stream>>>(z_mask, pos4, w1a, b1a, y4);
  l3_kernel<<<2048, 256, 0, stream>>>(y4, pos3, src3, w1a, w1b, b1b, x3f);
  y3_kernel<<<1024, 256, 0, stream>>>(x3f, pos3, w2a, b2a, y3);
  l2_kernel<<<8192, 256, 0, stream>>>(y3, pos2, src2, w2a, w2b, b2b, x2f);
  y2_kernel<<<2048, 256, 0, stream>>>(x2f, pos2, w3a, b3a, y2);
  l1_kernel<<<8192, 256, 0, stream>>>(y2, pos1, src1, w3a, w3b, b3b,
                                      wlin, blin, out);
}

// Round 2
// 242.549 us; speedup vs baseline: 1.0825x; 1.0385x over previous
//
#include <hip/hip_runtime.h>
#include <hip/hip_fp16.h>
#include <math.h>

#define N4C 32768
#define N3C 65536
#define N2C 131072
#define N1C 262144

typedef _Float16 f16x8 __attribute__((ext_vector_type(8)));
typedef float f32x4 __attribute__((ext_vector_type(4)));
typedef float f32x16 __attribute__((ext_vector_type(16)));

__device__ __forceinline__ f32x4 mfma16(f16x8 a, f16x8 b, f32x4 c) {
  return __builtin_amdgcn_mfma_f32_16x16x32_f16(a, b, c, 0, 0, 0);
}
__device__ __forceinline__ f32x16 mfma32(f16x8 a, f16x8 b, f32x16 c) {
  return __builtin_amdgcn_mfma_f32_32x32x16_f16(a, b, c, 0, 0, 0);
}

// fast celu (f32): max(x,0) + expm1(min(x,0)), branch-free
__device__ __forceinline__ float celuf(float x) {
  return fmaxf(x, 0.f) + (__expf(fminf(x, 0.f)) - 1.f);
}

__device__ __forceinline__ float logsigf(float x) {
  float e = __expf(-fabsf(x));
  return fminf(x, 0.f) - __logf(1.f + e);
}

__device__ __forceinline__ float max3f(float a, float b, float c) {
  return fmaxf(fmaxf(a, b), c);
}

// 2^x on f16 via v_exp_f16 (hexp2 -> single trans op)
__device__ __forceinline__ _Float16 exp2_16(_Float16 x) {
  __half h; __builtin_memcpy(&h, &x, 2);
  h = hexp2(h);
  _Float16 r; __builtin_memcpy(&r, &h, 2);
  return r;
}

// celu(x) + 1 = max(x,0) + exp(min(x,0)); the -1 is folded into the
// post-MFMA bias (bias -= sum_k Wb[k][n]), which commutes with edge-max.
__device__ __forceinline__ f16x8 celu8p1(f16x8 x) {
  f16x8 z = {};
  f16x8 mx = __builtin_elementwise_max(x, z);
  f16x8 mn = __builtin_elementwise_min(x, z) * (_Float16)1.44269504f;
#pragma unroll
  for (int i = 0; i < 8; ++i) mn[i] = exp2_16(mn[i]);
  return mx + mn;
}

// ---------------------------------------------------------------------------
// y4 = z @ W1a[:64] + b1a + pos4 @ W1a[64:67]  ([N4][64] f16)
// ---------------------------------------------------------------------------
__global__ __launch_bounds__(256) void y4_kernel(
    const float* __restrict__ z, const float* __restrict__ pos4,
    const float* __restrict__ w1a, const float* __restrict__ b1a,
    _Float16* __restrict__ y4) {
  const int lane = threadIdx.x & 63, wid = threadIdx.x >> 6;
  const int col = lane & 15, quad = lane >> 4;
  const int base = (blockIdx.x * 4 + wid) * 16;

  f16x8 Ba[2][4];
#pragma unroll
  for (int c = 0; c < 2; ++c)
#pragma unroll
    for (int t = 0; t < 4; ++t)
#pragma unroll
      for (int j = 0; j < 8; ++j)
        Ba[c][t][j] = (_Float16)w1a[(c * 32 + quad * 8 + j) * 64 + t * 16 + col];

  float wr[3][4];
#pragma unroll
  for (int c = 0; c < 3; ++c)
#pragma unroll
    for (int t = 0; t < 4; ++t)
      wr[c][t] = w1a[(64 + c) * 64 + t * 16 + col];

  float px[4], py[4], pz[4];
#pragma unroll
  for (int r = 0; r < 4; ++r) {
    const int row = base + quad * 4 + r;
    px[r] = pos4[row * 3 + 0];
    py[r] = pos4[row * 3 + 1];
    pz[r] = pos4[row * 3 + 2];
  }

  const float* zr = z + (size_t)(base + col) * 64;
  f16x8 A0, A1;
  {
    float4 f0 = *(const float4*)(zr + quad * 8);
    float4 f1 = *(const float4*)(zr + quad * 8 + 4);
    float4 f2 = *(const float4*)(zr + 32 + quad * 8);
    float4 f3 = *(const float4*)(zr + 32 + quad * 8 + 4);
    A0[0] = (_Float16)f0.x; A0[1] = (_Float16)f0.y; A0[2] = (_Float16)f0.z; A0[3] = (_Float16)f0.w;
    A0[4] = (_Float16)f1.x; A0[5] = (_Float16)f1.y; A0[6] = (_Float16)f1.z; A0[7] = (_Float16)f1.w;
    A1[0] = (_Float16)f2.x; A1[1] = (_Float16)f2.y; A1[2] = (_Float16)f2.z; A1[3] = (_Float16)f2.w;
    A1[4] = (_Float16)f3.x; A1[5] = (_Float16)f3.y; A1[6] = (_Float16)f3.z; A1[7] = (_Float16)f3.w;
  }
#pragma unroll
  for (int t = 0; t < 4; ++t) {
    f32x4 acc = {0.f, 0.f, 0.f, 0.f};
    acc = mfma16(A0, Ba[0][t], acc);
    acc = mfma16(A1, Ba[1][t], acc);
    const float bt = b1a[t * 16 + col];
#pragma unroll
    for (int r = 0; r < 4; ++r) {
      const float posterm =
          px[r] * wr[0][t] + py[r] * wr[1][t] + pz[r] * wr[2][t];
      y4[(size_t)(base + quad * 4 + r) * 64 + t * 16 + col] =
          (_Float16)(acc[r] + bt + posterm);
    }
  }
}

// ---------------------------------------------------------------------------
// y3 = x3 @ W2a[:32] + b2a + pos3 @ W2a[32:35]  ([N3][16] f16)
// ---------------------------------------------------------------------------
__global__ __launch_bounds__(256) void y3_kernel(
    const _Float16* __restrict__ x3f, const float* __restrict__ pos3,
    const float* __restrict__ w2a, const float* __restrict__ b2a,
    _Float16* __restrict__ y3) {
  const int lane = threadIdx.x & 63, wid = threadIdx.x >> 6;
  const int col = lane & 15, quad = lane >> 4;
  const int base = (blockIdx.x * 4 + wid) * 16;

  f16x8 B;
#pragma unroll
  for (int j = 0; j < 8; ++j) B[j] = (_Float16)w2a[(quad * 8 + j) * 16 + col];

  float wr[3];
#pragma unroll
  for (int c = 0; c < 3; ++c) wr[c] = w2a[(32 + c) * 16 + col];

  float px[4], py[4], pz[4];
#pragma unroll
  for (int r = 0; r < 4; ++r) {
    const int row = base + quad * 4 + r;
    px[r] = pos3[row * 3 + 0];
    py[r] = pos3[row * 3 + 1];
    pz[r] = pos3[row * 3 + 2];
  }

  f16x8 A = *(const f16x8*)(x3f + (size_t)(base + col) * 32 + quad * 8);
  f32x4 d = {0.f, 0.f, 0.f, 0.f};
  d = mfma16(A, B, d);
  const float bt = b2a[col];
#pragma unroll
  for (int r = 0; r < 4; ++r) {
    const float posterm = px[r] * wr[0] + py[r] * wr[1] + pz[r] * wr[2];
    y3[(size_t)(base + quad * 4 + r) * 16 + col] =
        (_Float16)(d[r] + bt + posterm);
  }
}

// ---------------------------------------------------------------------------
// y2 = x2 @ W3a[:16] + b3a + pos2 @ W3a[16:19]  ([N2][8] f16)
// ---------------------------------------------------------------------------
__global__ __launch_bounds__(256) void y2_kernel(
    const _Float16* __restrict__ x2f, const float* __restrict__ pos2,
    const float* __restrict__ w3a, const float* __restrict__ b3a,
    _Float16* __restrict__ y2) {
  const int lane = threadIdx.x & 63, wid = threadIdx.x >> 6;
  const int col = lane & 15, quad = lane >> 4;
  const int base = (blockIdx.x * 4 + wid) * 16;

  f16x8 B;
#pragma unroll
  for (int j = 0; j < 8; ++j) {
    int k = quad * 8 + j;
    B[j] = (k < 16 && col < 8) ? (_Float16)w3a[k * 8 + col] : (_Float16)0.f;
  }
  f16x8 A = *(const f16x8*)(x2f + (size_t)(base + col) * 16 + (quad & 1) * 8);
  f32x4 d = {0.f, 0.f, 0.f, 0.f};
  d = mfma16(A, B, d);
  if (col < 8) {
    float wr[3];
#pragma unroll
    for (int c = 0; c < 3; ++c) wr[c] = w3a[(16 + c) * 8 + col];
    const float bt = b3a[col];
#pragma unroll
    for (int r = 0; r < 4; ++r) {
      const int row = base + quad * 4 + r;
      const float posterm = pos2[row * 3 + 0] * wr[0] +
                            pos2[row * 3 + 1] * wr[1] +
                            pos2[row * 3 + 2] * wr[2];
      y2[(size_t)row * 8 + col] = (_Float16)(d[r] + bt + posterm);
    }
  }
}

// ---------------------------------------------------------------------------
// Level 3 gather, pair-pipelined (2 points per loop body).
// ---------------------------------------------------------------------------
__device__ __forceinline__ void l3_compute(
    int p, f16x8 A0, f16x8 A1, _Float16 q0, _Float16 q1, _Float16 q2,
    const f16x8 W0[3], const f16x8 W1[3], const f16x8 Bb[2][2],
    float biasB0, float biasB1, int lane, int col,
    _Float16* __restrict__ x3f) {
  A0 = celu8p1(A0 - (W0[0] * q0 + W0[1] * q1 + W0[2] * q2));
  A1 = celu8p1(A1 - (W1[0] * q0 + W1[1] * q1 + W1[2] * q2));

  f32x4 e0 = {0.f, 0.f, 0.f, 0.f}, e1 = {0.f, 0.f, 0.f, 0.f};
  e0 = mfma16(A0, Bb[0][0], e0);
  e0 = mfma16(A1, Bb[1][0], e0);
  e1 = mfma16(A0, Bb[0][1], e1);
  e1 = mfma16(A1, Bb[1][1], e1);

  float m0 = fmaxf(max3f(e0[0], e0[1], e0[2]), e0[3]);
  float m1 = fmaxf(max3f(e1[0], e1[1], e1[2]), e1[3]);
  m0 = fmaxf(m0, __shfl_xor(m0, 16, 64));
  m0 = fmaxf(m0, __shfl_xor(m0, 32, 64));
  m1 = fmaxf(m1, __shfl_xor(m1, 16, 64));
  m1 = fmaxf(m1, __shfl_xor(m1, 32, 64));
  if (lane < 16) {
    _Float16* row = x3f + (size_t)p * 32;
    row[col]      = (_Float16)celuf(m0 + biasB0);
    row[16 + col] = (_Float16)celuf(m1 + biasB1);
  }
}

__global__ __launch_bounds__(256) void l3_kernel(
    const _Float16* __restrict__ y4, const float* __restrict__ pos3,
    const int* __restrict__ src3, const float* __restrict__ w1a,
    const float* __restrict__ w1b, const float* __restrict__ b1b,
    _Float16* __restrict__ x3f) {
  const int lane = threadIdx.x & 63, wid = threadIdx.x >> 6;
  const int col = lane & 15, quad = lane >> 4;

  f16x8 Bb[2][2];
#pragma unroll
  for (int c = 0; c < 2; ++c)
#pragma unroll
    for (int t = 0; t < 2; ++t)
#pragma unroll
      for (int j = 0; j < 8; ++j)
        Bb[c][t][j] = (_Float16)w1b[(c * 32 + quad * 8 + j) * 32 + t * 16 + col];
  f16x8 W0[3], W1[3];
#pragma unroll
  for (int c = 0; c < 3; ++c)
#pragma unroll
    for (int j = 0; j < 8; ++j) {
      W0[c][j] = (_Float16)w1a[(64 + c) * 64 + quad * 8 + j];
      W1[c][j] = (_Float16)w1a[(64 + c) * 64 + 32 + quad * 8 + j];
    }
  // celu-shift fold: bias -= sum_k w1b[k][col-chan]
  float s0 = 0.f, s1 = 0.f;
#pragma unroll 4
  for (int k = 0; k < 64; ++k) {
    s0 += w1b[k * 32 + col];
    s1 += w1b[k * 32 + 16 + col];
  }
  const float biasB0 = b1b[col] - s0, biasB1 = b1b[16 + col] - s1;

  const int gwave = blockIdx.x * 4 + wid;
  const int nw = gridDim.x << 2;

#pragma unroll 1
  for (int p = gwave; p < N3C; p += 2 * nw) {
    const int p2 = p + nw;
    const int upa = __builtin_amdgcn_readfirstlane(p);
    const int upb = __builtin_amdgcn_readfirstlane(p2);
    const int sa = src3[p * 16 + col];
    const int sb = src3[p2 * 16 + col];

    f16x8 A0a = *(const f16x8*)(y4 + (size_t)sa * 64 + quad * 8);
    f16x8 A1a = *(const f16x8*)(y4 + (size_t)sa * 64 + 32 + quad * 8);
    f16x8 A0b = *(const f16x8*)(y4 + (size_t)sb * 64 + quad * 8);
    f16x8 A1b = *(const f16x8*)(y4 + (size_t)sb * 64 + 32 + quad * 8);

    const _Float16 qa0 = (_Float16)pos3[upa * 3 + 0];
    const _Float16 qa1 = (_Float16)pos3[upa * 3 + 1];
    const _Float16 qa2 = (_Float16)pos3[upa * 3 + 2];
    const _Float16 qb0 = (_Float16)pos3[upb * 3 + 0];
    const _Float16 qb1 = (_Float16)pos3[upb * 3 + 1];
    const _Float16 qb2 = (_Float16)pos3[upb * 3 + 2];

    l3_compute(p,  A0a, A1a, qa0, qa1, qa2, W0, W1, Bb, biasB0, biasB1,
               lane, col, x3f);
    l3_compute(p2, A0b, A1b, qb0, qb1, qb2, W0, W1, Bb, biasB0, biasB1,
               lane, col, x3f);
  }
}

// ---------------------------------------------------------------------------
// Level 2 gather, pair-pipelined: 2 points/wave via mfma_32x32x16, x2 ILP.
// ---------------------------------------------------------------------------
__device__ __forceinline__ void l2_compute(
    int pr, f16x8 A_in, _Float16 q0, _Float16 q1, _Float16 q2,
    const f16x8 W[3], f16x8 Bb, float biasB, int kh, int n,
    _Float16* __restrict__ x2f) {
  f16x8 A = celu8p1(A_in - (W[0] * q0 + W[1] * q1 + W[2] * q2));
  f32x16 acc = {};
  acc = mfma32(A, Bb, acc);

  float mA = fmaxf(max3f(max3f(acc[0], acc[1], acc[2]),
                         max3f(acc[3], acc[4], acc[5]), acc[6]), acc[7]);
  float mB = fmaxf(max3f(max3f(acc[8], acc[9], acc[10]),
                         max3f(acc[11], acc[12], acc[13]), acc[14]), acc[15]);
  mA = fmaxf(mA, __shfl_xor(mA, 32, 64));
  mB = fmaxf(mB, __shfl_xor(mB, 32, 64));

  if (n < 16) {
    const float m = kh ? mB : mA;
    x2f[(size_t)(2 * pr + kh) * 16 + n] = (_Float16)celuf(m + biasB);
  }
}

__global__ __launch_bounds__(256) void l2_kernel(
    const _Float16* __restrict__ y3, const float* __restrict__ pos2,
    const int* __restrict__ src2, const float* __restrict__ w2a,
    const float* __restrict__ w2b, const float* __restrict__ b2b,
    _Float16* __restrict__ x2f) {
  const int lane = threadIdx.x & 63, wid = threadIdx.x >> 6;
  const int n = lane & 31;
  const int e = lane & 15;
  const int h = (lane >> 4) & 1;
  const int kh = lane >> 5;

  f16x8 Bb;
#pragma unroll
  for (int j = 0; j < 8; ++j)
    Bb[j] = (n < 16) ? (_Float16)w2b[(kh * 8 + j) * 16 + n] : (_Float16)0.f;
  f16x8 W[3];
#pragma unroll
  for (int c = 0; c < 3; ++c)
#pragma unroll
    for (int j = 0; j < 8; ++j)
      W[c][j] = (_Float16)w2a[(32 + c) * 16 + kh * 8 + j];
  // celu-shift fold
  float ws = 0.f;
#pragma unroll
  for (int k = 0; k < 16; ++k) ws += w2b[k * 16 + (n & 15)];
  const float biasB = b2b[n & 15] - ws;

  const int gwave = blockIdx.x * 4 + wid;
  const int nw = gridDim.x << 2;

#pragma unroll 1
  for (int pr = gwave; pr < N2C / 2; pr += 2 * nw) {
    const int pr2 = pr + nw;
    const int pa = 2 * pr + h, pb = 2 * pr2 + h;
    const int sa = src2[pa * 16 + e];
    const int sb = src2[pb * 16 + e];

    f16x8 Aa = *(const f16x8*)(y3 + (size_t)sa * 16 + kh * 8);
    f16x8 Ab = *(const f16x8*)(y3 + (size_t)sb * 16 + kh * 8);

    const _Float16 qa0 = (_Float16)pos2[pa * 3 + 0];
    const _Float16 qa1 = (_Float16)pos2[pa * 3 + 1];
    const _Float16 qa2 = (_Float16)pos2[pa * 3 + 2];
    const _Float16 qb0 = (_Float16)pos2[pb * 3 + 0];
    const _Float16 qb1 = (_Float16)pos2[pb * 3 + 1];
    const _Float16 qb2 = (_Float16)pos2[pb * 3 + 2];

    l2_compute(pr,  Aa, qa0, qa1, qa2, W, Bb, biasB, kh, n, x2f);
    l2_compute(pr2, Ab, qb0, qb1, qb2, W, Bb, biasB, kh, n, x2f);
  }
}

// ---------------------------------------------------------------------------
// Level 1 gather, pair-pipelined: 4 points/wave via block-diag mfma_32x32x16.
// ---------------------------------------------------------------------------
__device__ __forceinline__ void l1_compute(
    int pb, f16x8 A_in, _Float16 q0, _Float16 q1, _Float16 q2,
    const f16x8 W[3], f16x8 Bb, float biasB, float wl, float bl, int lane,
    float* __restrict__ out) {
  f16x8 A = celu8p1(A_in - (W[0] * q0 + W[1] * q1 + W[2] * q2));
  f32x16 acc = {};
  acc = mfma32(A, Bb, acc);

  float mA = fmaxf(max3f(max3f(acc[0], acc[1], acc[2]),
                         max3f(acc[3], acc[4], acc[5]), acc[6]), acc[7]);
  float mB = fmaxf(max3f(max3f(acc[8], acc[9], acc[10]),
                         max3f(acc[11], acc[12], acc[13]), acc[14]), acc[15]);
  mA = fmaxf(mA, __shfl_xor(mA, 32, 64));
  mB = fmaxf(mB, __shfl_xor(mB, 32, 64));

  float tA = celuf(mA + biasB) * wl;  // wl==0 for n>=16
  float tB = celuf(mB + biasB) * wl;
  tA += __shfl_xor(tA, 1, 64);
  tA += __shfl_xor(tA, 2, 64);
  tA += __shfl_xor(tA, 4, 64);
  tB += __shfl_xor(tB, 1, 64);
  tB += __shfl_xor(tB, 2, 64);
  tB += __shfl_xor(tB, 4, 64);
  if (lane == 0) {
    float2 o; o.x = logsigf(tA + bl); o.y = logsigf(tB + bl);
    *(float2*)(out + pb) = o;
  } else if (lane == 8) {
    float2 o; o.x = logsigf(tA + bl); o.y = logsigf(tB + bl);
    *(float2*)(out + pb + 2) = o;
  }
}

__global__ __launch_bounds__(256) void l1_kernel(
    const _Float16* __restrict__ y2, const float* __restrict__ pos1,
    const int* __restrict__ src1, const float* __restrict__ w3a,
    const float* __restrict__ w3b, const float* __restrict__ b3b,
    const float* __restrict__ wlin, const float* __restrict__ blin,
    float* __restrict__ out) {
  const int lane = threadIdx.x & 63, wid = threadIdx.x >> 6;
  const int m = lane & 31;
  const int e = lane & 15;
  const int h = (lane >> 4) & 1;
  const int kh = lane >> 5;
  const int g = 2 * kh + h;

  f16x8 Bb;
  const int n = m;
#pragma unroll
  for (int j = 0; j < 8; ++j)
    Bb[j] = (n < 16 && (n >> 3) == kh) ? (_Float16)w3b[j * 8 + (n & 7)]
                                       : (_Float16)0.f;
  f16x8 W[3];
#pragma unroll
  for (int c = 0; c < 3; ++c)
#pragma unroll
    for (int j = 0; j < 8; ++j)
      W[c][j] = (_Float16)w3a[(16 + c) * 8 + j];
  // celu-shift fold
  float ws = 0.f;
#pragma unroll
  for (int j = 0; j < 8; ++j) ws += w3b[j * 8 + (n & 7)];
  const float biasB = (n < 16) ? b3b[n & 7] - ws : 0.f;
  const float wl = (n < 16) ? wlin[n & 7] : 0.f;
  const float bl = blin[0];

  const int gwave = blockIdx.x * 4 + wid;
  const int nw = gridDim.x << 2;

#pragma unroll 1
  for (int q = gwave; q < N1C / 4; q += 2 * nw) {
    const int q2 = q + nw;
    const int pba = q * 4, pbb = q2 * 4;
    const int pa = pba + g, pb = pbb + g;
    const int sa = src1[pa * 16 + e];
    const int sb = src1[pb * 16 + e];

    f16x8 Aa = *(const f16x8*)(y2 + (size_t)sa * 8);
    f16x8 Ab = *(const f16x8*)(y2 + (size_t)sb * 8);

    const _Float16 qa0 = (_Float16)(pos1[pa * 3 + 0]);
    const _Float16 qa1 = (_Float16)(pos1[pa * 3 + 1]);
    const _Float16 qa2 = (_Float16)(pos1[pa * 3 + 2]);
    const _Float16 qb0 = (_Float16)(pos1[pb * 3 + 0]);
    const _Float16 qb1 = (_Float16)(pos1[pb * 3 + 1]);
    const _Float16 qb2 = (_Float16)(pos1[pb * 3 + 2]);

    l1_compute(pba, Aa, qa0, qa1, qa2, W, Bb, biasB, wl, bl, lane, out);
    l1_compute(pbb, Ab, qb0, qb1, qb2, W, Bb, biasB, wl, bl, lane, out);
  }
}

extern "C" void kernel_launch(void* const* d_in, const int* in_sizes, int n_in,
                              void* d_out, int out_size, void* d_ws, size_t ws_size,
                              hipStream_t stream) {
  const float* z_mask = (const float*)d_in[0];
  const float* pos4 = (const float*)d_in[1];
  const float* pos3 = (const float*)d_in[2];
  const float* pos2 = (const float*)d_in[3];
  const float* pos1 = (const float*)d_in[4];
  const float* w1a = (const float*)d_in[9];
  const float* b1a = (const float*)d_in[10];
  const float* w1b = (const float*)d_in[11];
  const float* b1b = (const float*)d_in[12];
  const float* w2a = (const float*)d_in[13];
  const float* b2a = (const float*)d_in[14];
  const float* w2b = (const float*)d_in[15];
  const float* b2b = (const float*)d_in[16];
  const float* w3a = (const float*)d_in[17];
  const float* b3a = (const float*)d_in[18];
  const float* w3b = (const float*)d_in[19];
  const float* b3b = (const float*)d_in[20];
  const float* wlin = (const float*)d_in[21];
  const float* blin = (const float*)d_in[22];
  const int* src3 = (const int*)d_in[23];
  const int* src2 = (const int*)d_in[25];
  const int* src1 = (const int*)d_in[27];

  // ws (16 MB): Y4 4 | x3f 4 | Y3 2 | x2f 4 | Y2 2
  char* w = (char*)d_ws;
  _Float16* y4  = (_Float16*)(w);                      // [N4][64]
  _Float16* x3f = (_Float16*)(w + (4u << 20));         // [N3][32]
  _Float16* y3  = (_Float16*)(w + (8u << 20));         // [N3][16]
  _Float16* x2f = (_Float16*)(w + (10u << 20));        // [N2][16]
  _Float16* y2  = (_Float16*)(w + (14u << 20));        // [N2][8]
  float* out = (float*)d_out;

  y4_kernel<<<512, 256, 0, stream>>>(z_mask, pos4, w1a, b1a, y4);
  l3_kernel<<<2048, 256, 0, stream>>>(y4, pos3, src3, w1a, w1b, b1b, x3f);
  y3_kernel<<<1024, 256, 0, stream>>>(x3f, pos3, w2a, b2a, y3);
  l2_kernel<<<2048, 256, 0, stream>>>(y3, pos2, src2, w2a, w2b, b2b, x2f);
  y2_kernel<<<2048, 256, 0, stream>>>(x2f, pos2, w3a, b3a, y2);
  l1_kernel<<<2048, 256, 0, stream>>>(y2, pos1, src1, w3a, w3b, b3b,
                                      wlin, blin, out);
}

// Round 3
// 234.980 us; speedup vs baseline: 1.1174x; 1.0322x over previous
//
#include <hip/hip_runtime.h>
#include <hip/hip_fp16.h>
#include <math.h>

#define N4C 32768
#define N3C 65536
#define N2C 131072
#define N1C 262144

typedef _Float16 f16x8 __attribute__((ext_vector_type(8)));
typedef float f32x4 __attribute__((ext_vector_type(4)));
typedef float f32x16 __attribute__((ext_vector_type(16)));

__device__ __forceinline__ f32x4 mfma16(f16x8 a, f16x8 b, f32x4 c) {
  return __builtin_amdgcn_mfma_f32_16x16x32_f16(a, b, c, 0, 0, 0);
}
__device__ __forceinline__ f32x16 mfma32(f16x8 a, f16x8 b, f32x16 c) {
  return __builtin_amdgcn_mfma_f32_32x32x16_f16(a, b, c, 0, 0, 0);
}

// fast celu (f32): max(x,0) + expm1(min(x,0)), branch-free
__device__ __forceinline__ float celuf(float x) {
  return fmaxf(x, 0.f) + (__expf(fminf(x, 0.f)) - 1.f);
}

__device__ __forceinline__ float logsigf(float x) {
  float e = __expf(-fabsf(x));
  return fminf(x, 0.f) - __logf(1.f + e);
}

__device__ __forceinline__ float max3f(float a, float b, float c) {
  return fmaxf(fmaxf(a, b), c);
}

// 2^x on f16 via v_exp_f16
__device__ __forceinline__ _Float16 exp2_16(_Float16 x) {
  __half h; __builtin_memcpy(&h, &x, 2);
  h = hexp2(h);
  _Float16 r; __builtin_memcpy(&r, &h, 2);
  return r;
}

// celu(x) + 1 = max(x,0) + exp(min(x,0)); the -1 is folded into the
// post-MFMA bias (bias -= sum_k Wb[k][n]), which commutes with edge-max.
__device__ __forceinline__ f16x8 celu8p1(f16x8 x) {
  f16x8 z = {};
  f16x8 mx = __builtin_elementwise_max(x, z);
  f16x8 mn = __builtin_elementwise_min(x, z) * (_Float16)1.44269504f;
#pragma unroll
  for (int i = 0; i < 8; ++i) mn[i] = exp2_16(mn[i]);
  return mx + mn;
}

// ---------------------------------------------------------------------------
// y4 = z @ W1a[:64] + b1a + pos4 @ W1a[64:67]  ([N4][64] f16)
// Fused tail blocks: vt3[p][k] = pos3[p] . W1a[64:67][k]  ([N3][64] f16)
// ---------------------------------------------------------------------------
__global__ __launch_bounds__(256) void y4_kernel(
    const float* __restrict__ z, const float* __restrict__ pos4,
    const float* __restrict__ pos3, const float* __restrict__ w1a,
    const float* __restrict__ b1a, _Float16* __restrict__ y4,
    _Float16* __restrict__ vt3) {
  if (blockIdx.x >= 512) {
    // vt3: 2048 blocks * 256 threads = N3 * 8 (each thread: 8 channels)
    const int idx = (blockIdx.x - 512) * 256 + threadIdx.x;
    const int p = idx >> 3, seg = (idx & 7) * 8;
    const float q0 = pos3[p * 3 + 0];
    const float q1 = pos3[p * 3 + 1];
    const float q2 = pos3[p * 3 + 2];
    f16x8 v;
#pragma unroll
    for (int j = 0; j < 8; ++j) {
      const int k = seg + j;
      v[j] = (_Float16)(w1a[64 * 64 + k] * q0 + w1a[65 * 64 + k] * q1 +
                        w1a[66 * 64 + k] * q2);
    }
    *(f16x8*)(vt3 + (size_t)p * 64 + seg) = v;
    return;
  }
  const int lane = threadIdx.x & 63, wid = threadIdx.x >> 6;
  const int col = lane & 15, quad = lane >> 4;
  const int base = (blockIdx.x * 4 + wid) * 16;

  f16x8 Ba[2][4];
#pragma unroll
  for (int c = 0; c < 2; ++c)
#pragma unroll
    for (int t = 0; t < 4; ++t)
#pragma unroll
      for (int j = 0; j < 8; ++j)
        Ba[c][t][j] = (_Float16)w1a[(c * 32 + quad * 8 + j) * 64 + t * 16 + col];

  float wr[3][4];
#pragma unroll
  for (int c = 0; c < 3; ++c)
#pragma unroll
    for (int t = 0; t < 4; ++t)
      wr[c][t] = w1a[(64 + c) * 64 + t * 16 + col];

  float px[4], py[4], pz[4];
#pragma unroll
  for (int r = 0; r < 4; ++r) {
    const int row = base + quad * 4 + r;
    px[r] = pos4[row * 3 + 0];
    py[r] = pos4[row * 3 + 1];
    pz[r] = pos4[row * 3 + 2];
  }

  const float* zr = z + (size_t)(base + col) * 64;
  f16x8 A0, A1;
  {
    float4 f0 = *(const float4*)(zr + quad * 8);
    float4 f1 = *(const float4*)(zr + quad * 8 + 4);
    float4 f2 = *(const float4*)(zr + 32 + quad * 8);
    float4 f3 = *(const float4*)(zr + 32 + quad * 8 + 4);
    A0[0] = (_Float16)f0.x; A0[1] = (_Float16)f0.y; A0[2] = (_Float16)f0.z; A0[3] = (_Float16)f0.w;
    A0[4] = (_Float16)f1.x; A0[5] = (_Float16)f1.y; A0[6] = (_Float16)f1.z; A0[7] = (_Float16)f1.w;
    A1[0] = (_Float16)f2.x; A1[1] = (_Float16)f2.y; A1[2] = (_Float16)f2.z; A1[3] = (_Float16)f2.w;
    A1[4] = (_Float16)f3.x; A1[5] = (_Float16)f3.y; A1[6] = (_Float16)f3.z; A1[7] = (_Float16)f3.w;
  }
#pragma unroll
  for (int t = 0; t < 4; ++t) {
    f32x4 acc = {0.f, 0.f, 0.f, 0.f};
    acc = mfma16(A0, Ba[0][t], acc);
    acc = mfma16(A1, Ba[1][t], acc);
    const float bt = b1a[t * 16 + col];
#pragma unroll
    for (int r = 0; r < 4; ++r) {
      const float posterm =
          px[r] * wr[0][t] + py[r] * wr[1][t] + pz[r] * wr[2][t];
      y4[(size_t)(base + quad * 4 + r) * 64 + t * 16 + col] =
          (_Float16)(acc[r] + bt + posterm);
    }
  }
}

// ---------------------------------------------------------------------------
// y3 = x3 @ W2a[:32] + b2a + pos3 @ W2a[32:35]  ([N3][16] f16)
// Fused tail blocks: vt2[p][k] = pos2[p] . W2a[32:35][k]  ([N2][16] f16)
// ---------------------------------------------------------------------------
__global__ __launch_bounds__(256) void y3_kernel(
    const _Float16* __restrict__ x3f, const float* __restrict__ pos3,
    const float* __restrict__ pos2, const float* __restrict__ w2a,
    const float* __restrict__ b2a, _Float16* __restrict__ y3,
    _Float16* __restrict__ vt2) {
  if (blockIdx.x >= 1024) {
    // vt2: 1024 blocks * 256 = N2 * 2 (each thread: 8 channels)
    const int idx = (blockIdx.x - 1024) * 256 + threadIdx.x;
    const int p = idx >> 1, seg = (idx & 1) * 8;
    const float q0 = pos2[p * 3 + 0];
    const float q1 = pos2[p * 3 + 1];
    const float q2 = pos2[p * 3 + 2];
    f16x8 v;
#pragma unroll
    for (int j = 0; j < 8; ++j) {
      const int k = seg + j;
      v[j] = (_Float16)(w2a[32 * 16 + k] * q0 + w2a[33 * 16 + k] * q1 +
                        w2a[34 * 16 + k] * q2);
    }
    *(f16x8*)(vt2 + (size_t)p * 16 + seg) = v;
    return;
  }
  const int lane = threadIdx.x & 63, wid = threadIdx.x >> 6;
  const int col = lane & 15, quad = lane >> 4;
  const int base = (blockIdx.x * 4 + wid) * 16;

  f16x8 B;
#pragma unroll
  for (int j = 0; j < 8; ++j) B[j] = (_Float16)w2a[(quad * 8 + j) * 16 + col];

  float wr[3];
#pragma unroll
  for (int c = 0; c < 3; ++c) wr[c] = w2a[(32 + c) * 16 + col];

  float px[4], py[4], pz[4];
#pragma unroll
  for (int r = 0; r < 4; ++r) {
    const int row = base + quad * 4 + r;
    px[r] = pos3[row * 3 + 0];
    py[r] = pos3[row * 3 + 1];
    pz[r] = pos3[row * 3 + 2];
  }

  f16x8 A = *(const f16x8*)(x3f + (size_t)(base + col) * 32 + quad * 8);
  f32x4 d = {0.f, 0.f, 0.f, 0.f};
  d = mfma16(A, B, d);
  const float bt = b2a[col];
#pragma unroll
  for (int r = 0; r < 4; ++r) {
    const float posterm = px[r] * wr[0] + py[r] * wr[1] + pz[r] * wr[2];
    y3[(size_t)(base + quad * 4 + r) * 16 + col] =
        (_Float16)(d[r] + bt + posterm);
  }
}

// ---------------------------------------------------------------------------
// y2 = x2 @ W3a[:16] + b3a + pos2 @ W3a[16:19]  ([N2][8] f16)
// Fused tail blocks: vt1[p][k] = pos1[p] . W3a[16:19][k]  ([N1][8] f16)
// ---------------------------------------------------------------------------
__global__ __launch_bounds__(256) void y2_kernel(
    const _Float16* __restrict__ x2f, const float* __restrict__ pos2,
    const float* __restrict__ pos1, const float* __restrict__ w3a,
    const float* __restrict__ b3a, _Float16* __restrict__ y2,
    _Float16* __restrict__ vt1) {
  if (blockIdx.x >= 2048) {
    // vt1: 1024 blocks * 256 = N1 (each thread: full 8-channel row)
    const int p = (blockIdx.x - 2048) * 256 + threadIdx.x;
    const float q0 = pos1[p * 3 + 0];
    const float q1 = pos1[p * 3 + 1];
    const float q2 = pos1[p * 3 + 2];
    f16x8 v;
#pragma unroll
    for (int k = 0; k < 8; ++k)
      v[k] = (_Float16)(w3a[16 * 8 + k] * q0 + w3a[17 * 8 + k] * q1 +
                        w3a[18 * 8 + k] * q2);
    *(f16x8*)(vt1 + (size_t)p * 8) = v;
    return;
  }
  const int lane = threadIdx.x & 63, wid = threadIdx.x >> 6;
  const int col = lane & 15, quad = lane >> 4;
  const int base = (blockIdx.x * 4 + wid) * 16;

  f16x8 B;
#pragma unroll
  for (int j = 0; j < 8; ++j) {
    int k = quad * 8 + j;
    B[j] = (k < 16 && col < 8) ? (_Float16)w3a[k * 8 + col] : (_Float16)0.f;
  }
  f16x8 A = *(const f16x8*)(x2f + (size_t)(base + col) * 16 + (quad & 1) * 8);
  f32x4 d = {0.f, 0.f, 0.f, 0.f};
  d = mfma16(A, B, d);
  if (col < 8) {
    float wr[3];
#pragma unroll
    for (int c = 0; c < 3; ++c) wr[c] = w3a[(16 + c) * 8 + col];
    const float bt = b3a[col];
#pragma unroll
    for (int r = 0; r < 4; ++r) {
      const int row = base + quad * 4 + r;
      const float posterm = pos2[row * 3 + 0] * wr[0] +
                            pos2[row * 3 + 1] * wr[1] +
                            pos2[row * 3 + 2] * wr[2];
      y2[(size_t)row * 8 + col] = (_Float16)(d[r] + bt + posterm);
    }
  }
}

// ---------------------------------------------------------------------------
// Level 3 gather: 2 points/wave via mfma_32x32x16, vtab position fold.
// A row m = e + 16h (edge e of point pb+h); k = 64 mid-channels over 4 frags.
// ---------------------------------------------------------------------------
__global__ __launch_bounds__(256) void l3_kernel(
    const _Float16* __restrict__ y4, const _Float16* __restrict__ vt3,
    const int* __restrict__ src3, const float* __restrict__ w1b,
    const float* __restrict__ b1b, _Float16* __restrict__ x3f) {
  const int lane = threadIdx.x & 63, wid = threadIdx.x >> 6;
  const int n = lane & 31;   // B col (out channel) and A row (e + 16h)
  const int kh = lane >> 5;  // k-half

  // B frags: B[ks][j] = w1b[k][n], k = ks*16 + kh*8 + j
  f16x8 Bb[4];
#pragma unroll
  for (int ks = 0; ks < 4; ++ks)
#pragma unroll
    for (int j = 0; j < 8; ++j)
      Bb[ks][j] = (_Float16)w1b[(ks * 16 + kh * 8 + j) * 32 + n];

  // celu-shift fold: biasB = b1b[n] - sum_k w1b[k][n]; k distributed over kh
  float s = 0.f;
#pragma unroll 4
  for (int k = 0; k < 32; ++k) s += w1b[(kh * 32 + k) * 32 + n];
  s += __shfl_xor(s, 32, 64);
  const float biasB = b1b[n] - s;

  const int gwave = blockIdx.x * 4 + wid;
  const int nw = gridDim.x << 2;

#pragma unroll 1
  for (int pb = gwave * 2; pb < N3C; pb += nw * 2) {
    const int s1 = src3[pb * 16 + n];  // = (pb + (n>>4))*16 + (n&15), coalesced
    const int p = pb + (n >> 4);
    const _Float16* yrow = y4 + (size_t)s1 * 64 + kh * 8;
    const _Float16* vrow = vt3 + (size_t)p * 64 + kh * 8;

    f16x8 A[4];
#pragma unroll
    for (int ks = 0; ks < 4; ++ks)
      A[ks] = *(const f16x8*)(yrow + ks * 16) - *(const f16x8*)(vrow + ks * 16);
#pragma unroll
    for (int ks = 0; ks < 4; ++ks) A[ks] = celu8p1(A[ks]);

    f32x16 acc = {};
#pragma unroll
    for (int ks = 0; ks < 4; ++ks) acc = mfma32(A[ks], Bb[ks], acc);

    // regs 0..7 -> rows <16 (point pb), regs 8..15 -> rows >=16 (point pb+1)
    float mA = fmaxf(max3f(max3f(acc[0], acc[1], acc[2]),
                           max3f(acc[3], acc[4], acc[5]), acc[6]), acc[7]);
    float mB = fmaxf(max3f(max3f(acc[8], acc[9], acc[10]),
                           max3f(acc[11], acc[12], acc[13]), acc[14]), acc[15]);
    mA = fmaxf(mA, __shfl_xor(mA, 32, 64));
    mB = fmaxf(mB, __shfl_xor(mB, 32, 64));

    const float mv = kh ? mB : mA;
    x3f[(size_t)(pb + kh) * 32 + n] = (_Float16)celuf(mv + biasB);
  }
}

// ---------------------------------------------------------------------------
// Level 2 gather, pair-pipelined: 2 points/wave via mfma_32x32x16, vtab fold.
// ---------------------------------------------------------------------------
__device__ __forceinline__ void l2_compute(
    int pr, f16x8 A_in, f16x8 vt, f16x8 Bb, float biasB, int kh, int n,
    _Float16* __restrict__ x2f) {
  f16x8 A = celu8p1(A_in - vt);
  f32x16 acc = {};
  acc = mfma32(A, Bb, acc);

  float mA = fmaxf(max3f(max3f(acc[0], acc[1], acc[2]),
                         max3f(acc[3], acc[4], acc[5]), acc[6]), acc[7]);
  float mB = fmaxf(max3f(max3f(acc[8], acc[9], acc[10]),
                         max3f(acc[11], acc[12], acc[13]), acc[14]), acc[15]);
  mA = fmaxf(mA, __shfl_xor(mA, 32, 64));
  mB = fmaxf(mB, __shfl_xor(mB, 32, 64));

  if (n < 16) {
    const float m = kh ? mB : mA;
    x2f[(size_t)(2 * pr + kh) * 16 + n] = (_Float16)celuf(m + biasB);
  }
}

__global__ __launch_bounds__(256) void l2_kernel(
    const _Float16* __restrict__ y3, const _Float16* __restrict__ vt2,
    const int* __restrict__ src2, const float* __restrict__ w2b,
    const float* __restrict__ b2b, _Float16* __restrict__ x2f) {
  const int lane = threadIdx.x & 63, wid = threadIdx.x >> 6;
  const int n = lane & 31;
  const int e = lane & 15;
  const int h = (lane >> 4) & 1;
  const int kh = lane >> 5;

  f16x8 Bb;
#pragma unroll
  for (int j = 0; j < 8; ++j)
    Bb[j] = (n < 16) ? (_Float16)w2b[(kh * 8 + j) * 16 + n] : (_Float16)0.f;
  // celu-shift fold
  float ws = 0.f;
#pragma unroll
  for (int k = 0; k < 16; ++k) ws += w2b[k * 16 + (n & 15)];
  const float biasB = b2b[n & 15] - ws;

  const int gwave = blockIdx.x * 4 + wid;
  const int nw = gridDim.x << 2;

#pragma unroll 1
  for (int pr = gwave; pr < N2C / 2; pr += 2 * nw) {
    const int pr2 = pr + nw;
    const int pa = 2 * pr + h, pb = 2 * pr2 + h;
    const int sa = src2[pa * 16 + e];
    const int sb = src2[pb * 16 + e];

    f16x8 Aa = *(const f16x8*)(y3 + (size_t)sa * 16 + kh * 8);
    f16x8 Ab = *(const f16x8*)(y3 + (size_t)sb * 16 + kh * 8);
    f16x8 va = *(const f16x8*)(vt2 + (size_t)pa * 16 + kh * 8);
    f16x8 vb = *(const f16x8*)(vt2 + (size_t)pb * 16 + kh * 8);

    l2_compute(pr,  Aa, va, Bb, biasB, kh, n, x2f);
    l2_compute(pr2, Ab, vb, Bb, biasB, kh, n, x2f);
  }
}

// ---------------------------------------------------------------------------
// Level 1 gather, pair-pipelined: 4 points/wave via block-diag mfma_32x32x16,
// vtab position fold.
// ---------------------------------------------------------------------------
__device__ __forceinline__ void l1_compute(
    int pb, f16x8 A_in, f16x8 vt, f16x8 Bb, float biasB, float wl, float bl,
    int lane, float* __restrict__ out) {
  f16x8 A = celu8p1(A_in - vt);
  f32x16 acc = {};
  acc = mfma32(A, Bb, acc);

  float mA = fmaxf(max3f(max3f(acc[0], acc[1], acc[2]),
                         max3f(acc[3], acc[4], acc[5]), acc[6]), acc[7]);
  float mB = fmaxf(max3f(max3f(acc[8], acc[9], acc[10]),
                         max3f(acc[11], acc[12], acc[13]), acc[14]), acc[15]);
  mA = fmaxf(mA, __shfl_xor(mA, 32, 64));
  mB = fmaxf(mB, __shfl_xor(mB, 32, 64));

  float tA = celuf(mA + biasB) * wl;  // wl==0 for n>=16
  float tB = celuf(mB + biasB) * wl;
  tA += __shfl_xor(tA, 1, 64);
  tA += __shfl_xor(tA, 2, 64);
  tA += __shfl_xor(tA, 4, 64);
  tB += __shfl_xor(tB, 1, 64);
  tB += __shfl_xor(tB, 2, 64);
  tB += __shfl_xor(tB, 4, 64);
  if (lane == 0) {
    float2 o; o.x = logsigf(tA + bl); o.y = logsigf(tB + bl);
    *(float2*)(out + pb) = o;
  } else if (lane == 8) {
    float2 o; o.x = logsigf(tA + bl); o.y = logsigf(tB + bl);
    *(float2*)(out + pb + 2) = o;
  }
}

__global__ __launch_bounds__(256) void l1_kernel(
    const _Float16* __restrict__ y2, const _Float16* __restrict__ vt1,
    const int* __restrict__ src1, const float* __restrict__ w3b,
    const float* __restrict__ b3b, const float* __restrict__ wlin,
    const float* __restrict__ blin, float* __restrict__ out) {
  const int lane = threadIdx.x & 63, wid = threadIdx.x >> 6;
  const int m = lane & 31;
  const int e = lane & 15;
  const int h = (lane >> 4) & 1;
  const int kh = lane >> 5;
  const int g = 2 * kh + h;

  f16x8 Bb;
  const int n = m;
#pragma unroll
  for (int j = 0; j < 8; ++j)
    Bb[j] = (n < 16 && (n >> 3) == kh) ? (_Float16)w3b[j * 8 + (n & 7)]
                                       : (_Float16)0.f;
  // celu-shift fold
  float ws = 0.f;
#pragma unroll
  for (int j = 0; j < 8; ++j) ws += w3b[j * 8 + (n & 7)];
  const float biasB = (n < 16) ? b3b[n & 7] - ws : 0.f;
  const float wl = (n < 16) ? wlin[n & 7] : 0.f;
  const float bl = blin[0];

  const int gwave = blockIdx.x * 4 + wid;
  const int nw = gridDim.x << 2;

#pragma unroll 1
  for (int q = gwave; q < N1C / 4; q += 2 * nw) {
    const int q2 = q + nw;
    const int pba = q * 4, pbb = q2 * 4;
    const int pa = pba + g, pb = pbb + g;
    const int sa = src1[pa * 16 + e];
    const int sb = src1[pb * 16 + e];

    f16x8 Aa = *(const f16x8*)(y2 + (size_t)sa * 8);
    f16x8 Ab = *(const f16x8*)(y2 + (size_t)sb * 8);
    f16x8 va = *(const f16x8*)(vt1 + (size_t)pa * 8);
    f16x8 vb = *(const f16x8*)(vt1 + (size_t)pb * 8);

    l1_compute(pba, Aa, va, Bb, biasB, wl, bl, lane, out);
    l1_compute(pbb, Ab, vb, Bb, biasB, wl, bl, lane, out);
  }
}

extern "C" void kernel_launch(void* const* d_in, const int* in_sizes, int n_in,
                              void* d_out, int out_size, void* d_ws, size_t ws_size,
                              hipStream_t stream) {
  const float* z_mask = (const float*)d_in[0];
  const float* pos4 = (const float*)d_in[1];
  const float* pos3 = (const float*)d_in[2];
  const float* pos2 = (const float*)d_in[3];
  const float* pos1 = (const float*)d_in[4];
  const float* w1a = (const float*)d_in[9];
  const float* b1a = (const float*)d_in[10];
  const float* w1b = (const float*)d_in[11];
  const float* b1b = (const float*)d_in[12];
  const float* w2a = (const float*)d_in[13];
  const float* b2a = (const float*)d_in[14];
  const float* w2b = (const float*)d_in[15];
  const float* b2b = (const float*)d_in[16];
  const float* w3a = (const float*)d_in[17];
  const float* b3a = (const float*)d_in[18];
  const float* w3b = (const float*)d_in[19];
  const float* b3b = (const float*)d_in[20];
  const float* wlin = (const float*)d_in[21];
  const float* blin = (const float*)d_in[22];
  const int* src3 = (const int*)d_in[23];
  const int* src2 = (const int*)d_in[25];
  const int* src1 = (const int*)d_in[27];

  // ws (16 MB), lifetime-aliased:
  //   y4  [0,4M)   live y4k..l3      | vt3 [4M,12M) live y4k..l3
  //   x3f [12M,16M) live l3..y3k     | y3  [0,2M)   live y3k..l2
  //   vt2 [4M,8M)  live y3k..l2      | x2f [8M,12M) live l2..y2k
  //   y2  [2M,4M)  live y2k..l1      | vt1 [12M,16M) live y2k..l1
  char* w = (char*)d_ws;
  _Float16* y4  = (_Float16*)(w);
  _Float16* vt3 = (_Float16*)(w + (4u << 20));
  _Float16* x3f = (_Float16*)(w + (12u << 20));
  _Float16* y3  = (_Float16*)(w);
  _Float16* vt2 = (_Float16*)(w + (4u << 20));
  _Float16* x2f = (_Float16*)(w + (8u << 20));
  _Float16* y2  = (_Float16*)(w + (2u << 20));
  _Float16* vt1 = (_Float16*)(w + (12u << 20));
  float* out = (float*)d_out;

  y4_kernel<<<2560, 256, 0, stream>>>(z_mask, pos4, pos3, w1a, b1a, y4, vt3);
  l3_kernel<<<2048, 256, 0, stream>>>(y4, vt3, src3, w1b, b1b, x3f);
  y3_kernel<<<2048, 256, 0, stream>>>(x3f, pos3, pos2, w2a, b2a, y3, vt2);
  l2_kernel<<<2048, 256, 0, stream>>>(y3, vt2, src2, w2b, b2b, x2f);
  y2_kernel<<<3072, 256, 0, stream>>>(x2f, pos2, pos1, w3a, b3a, y2, vt1);
  l1_kernel<<<2048, 256, 0, stream>>>(y2, vt1, src1, w3b, b3b,
                                      wlin, blin, out);
}